// Round 4
// baseline (379.176 us; speedup 1.0000x reference)
//
#include <hip/hip_runtime.h>
#include <hip/hip_bf16.h>

typedef unsigned short u16;
typedef unsigned int u32;
typedef __attribute__((ext_vector_type(8))) short short8;
typedef __attribute__((ext_vector_type(16))) float floatx16;

#define MDIM 4096
#define NDIM 4096
#define KDIM 4096
#define BM 128
#define BN 128
#define BK 64

// ---------------- fp32 -> bf16 conversion, both matrices, one launch --------
__global__ __launch_bounds__(256) void cvt2_f32_bf16(const float* __restrict__ x,
                                                     const float* __restrict__ w,
                                                     u16* __restrict__ xa,
                                                     u16* __restrict__ wb) {
    const int half = gridDim.x >> 1;
    int b = blockIdx.x;
    const float* src = x;
    u16* dst = xa;
    if (b >= half) { src = w; dst = wb; b -= half; }
    const int i = b * 256 + threadIdx.x;           // float4 index
    float4 f = ((const float4*)src)[i];
    u32 ua = __float_as_uint(f.x), ub = __float_as_uint(f.y);
    u32 uc = __float_as_uint(f.z), ud = __float_as_uint(f.w);
    ushort4 o;                                     // RNE to bf16
    o.x = (u16)((ua + 0x7fffu + ((ua >> 16) & 1u)) >> 16);
    o.y = (u16)((ub + 0x7fffu + ((ub >> 16) & 1u)) >> 16);
    o.z = (u16)((uc + 0x7fffu + ((uc >> 16) & 1u)) >> 16);
    o.w = (u16)((ud + 0x7fffu + ((ud >> 16) & 1u)) >> 16);
    ((ushort4*)dst)[i] = o;
}

// ---------------- bf16 GEMM, C = A * B^T + bias ----------------
// Round-3 skeleton (BK=64, XOR-8 swizzle, post-barrier prefetch) with the
// MFMA shape switched 16x16x32 -> 32x32x16 (4060 vs 3377 FLOP/cyc/CU, m119).
// Wave tile 64x64 = 2x2 of 32x32 accumulators; same LDS bytes, half the
// MFMA instruction count.
typedef const __attribute__((address_space(1))) void* gas_ptr;
typedef __attribute__((address_space(3))) void* lds_ptr;

__global__ __launch_bounds__(256, 3) void gemm_bt_bias(const u16* __restrict__ A,
                                                       const u16* __restrict__ B,
                                                       const float* __restrict__ bias,
                                                       float* __restrict__ C) {
    __shared__ u16 lA[BM * BK];  // 16 KiB
    __shared__ u16 lB[BN * BK];  // 16 KiB

    const int t = threadIdx.x;
    const int bm0 = blockIdx.y * BM;
    const int bn0 = blockIdx.x * BN;

    const int wave = t >> 6;
    const int lane = t & 63;
    const int wm = (wave & 1) * 64;
    const int wn = (wave >> 1) * 64;
    const int r32 = lane & 31;         // row within 32-tile (A-m / B-n)
    const int h = lane >> 5;           // k-half selector

    floatx16 acc[2][2] = {};

    // staging: 4 stages per matrix; stage s, thread t -> linear idx = s*256+t,
    // row = idx>>3, slot = idx&7, fetch global chunk slot^(row&7).
    const u16* gA[4]; const u16* gB[4];
    u16* lAp[4]; u16* lBp[4];
#pragma unroll
    for (int s = 0; s < 4; ++s) {
        const int idx = s * 256 + t;
        const int row = idx >> 3;
        const int c = (idx & 7) ^ (row & 7);       // global k-chunk (8 elems)
        gA[s] = A + (size_t)(bm0 + row) * KDIM + c * 8;
        gB[s] = B + (size_t)(bn0 + row) * KDIM + c * 8;
        lAp[s] = &lA[(size_t)idx * 8];
        lBp[s] = &lB[(size_t)idx * 8];
    }

    // k0 = 0 stage
#pragma unroll
    for (int s = 0; s < 4; ++s) {
        __builtin_amdgcn_global_load_lds((gas_ptr)gA[s], (lds_ptr)lAp[s], 16, 0, 0);
        __builtin_amdgcn_global_load_lds((gas_ptr)gB[s], (lds_ptr)lBp[s], 16, 0, 0);
    }

    for (int k0 = 0; k0 < KDIM; k0 += BK) {
        __syncthreads();   // drains vmcnt(0): staging for k0 visible to all

        // A-frag (32x32x16): A[m = lane&31][k = (lane>>5)*8 + j]
        // logical k-chunk for step st = st*2 + h; LDS slot = chunk^(row&7)
        short8 af[2][4], bfr[2][4];
#pragma unroll
        for (int i = 0; i < 2; ++i) {
            const int row = wm + i * 32 + r32;
            const int sw = row & 7;
#pragma unroll
            for (int st = 0; st < 4; ++st)
                af[i][st] = *(const short8*)&lA[row * BK + (((st * 2 + h) ^ sw) * 8)];
        }
#pragma unroll
        for (int j = 0; j < 2; ++j) {
            const int row = wn + j * 32 + r32;
            const int sw = row & 7;
#pragma unroll
            for (int st = 0; st < 4; ++st)
                bfr[j][st] = *(const short8*)&lB[row * BK + (((st * 2 + h) ^ sw) * 8)];
        }

        __syncthreads();   // all waves' ds_reads done -> LDS reusable

        if (k0 + BK < KDIM) {
            const int ko = k0 + BK;
#pragma unroll
            for (int s = 0; s < 4; ++s) {
                __builtin_amdgcn_global_load_lds((gas_ptr)(gA[s] + ko), (lds_ptr)lAp[s], 16, 0, 0);
                __builtin_amdgcn_global_load_lds((gas_ptr)(gB[s] + ko), (lds_ptr)lBp[s], 16, 0, 0);
            }
        }

#pragma unroll
        for (int st = 0; st < 4; ++st)
#pragma unroll
            for (int i = 0; i < 2; ++i)
#pragma unroll
                for (int j = 0; j < 2; ++j)
                    acc[i][j] = __builtin_amdgcn_mfma_f32_32x32x16_bf16(af[i][st], bfr[j][st], acc[i][j], 0, 0, 0);
    }

    // epilogue: 32x32 C/D layout col=lane&31, row=(reg&3)+8*(reg>>2)+4*(lane>>5)
    // [m74/m101-verified]
#pragma unroll
    for (int i = 0; i < 2; ++i) {
#pragma unroll
        for (int j = 0; j < 2; ++j) {
            const int col = bn0 + wn + j * 32 + r32;
            const float bv = bias[col];
#pragma unroll
            for (int reg = 0; reg < 16; ++reg) {
                const int row = bm0 + wm + i * 32 + (reg & 3) + 8 * (reg >> 2) + 4 * h;
                C[(size_t)row * NDIM + col] = acc[i][j][reg] + bv;
            }
        }
    }
}

extern "C" void kernel_launch(void* const* d_in, const int* in_sizes, int n_in,
                              void* d_out, int out_size, void* d_ws, size_t ws_size,
                              hipStream_t stream) {
    const float* x = (const float*)d_in[0];      // (4096, 4096) fp32
    const float* w = (const float*)d_in[1];      // (4096, 4096) fp32, OUT x IN
    const float* bias = (const float*)d_in[2];   // (4096,) fp32
    float* out = (float*)d_out;                  // (4096, 4096) fp32

    u16* xa = (u16*)d_ws;                        // 32 MiB bf16 x
    u16* wb = xa + (size_t)MDIM * KDIM;          // 32 MiB bf16 W

    const int blocks_per_mat = (MDIM * KDIM) / 4 / 256;   // 16384
    cvt2_f32_bf16<<<blocks_per_mat * 2, 256, 0, stream>>>(x, w, xa, wb);

    dim3 grid(NDIM / BN, MDIM / BM);             // 32 x 32
    gemm_bt_bias<<<grid, dim3(256), 0, stream>>>(xa, wb, bias, out);
}

// Round 5
// 298.735 us; speedup vs baseline: 1.2693x; 1.2693x over previous
//
#include <hip/hip_runtime.h>
#include <hip/hip_bf16.h>

typedef unsigned short u16;
typedef unsigned int u32;
typedef __attribute__((ext_vector_type(8))) short short8;
typedef __attribute__((ext_vector_type(4))) float floatx4;

#define MDIM 4096
#define NDIM 4096
#define KDIM 4096
#define BM 128
#define BN 128
#define BK 64

// ---------------- fp32 -> bf16 conversion, both matrices, one launch --------
__global__ __launch_bounds__(256) void cvt2_f32_bf16(const float* __restrict__ x,
                                                     const float* __restrict__ w,
                                                     u16* __restrict__ xa,
                                                     u16* __restrict__ wb) {
    const int half = gridDim.x >> 1;
    int b = blockIdx.x;
    const float* src = x;
    u16* dst = xa;
    if (b >= half) { src = w; dst = wb; b -= half; }
    const int i = b * 256 + threadIdx.x;           // float4 index
    float4 f = ((const float4*)src)[i];
    u32 ua = __float_as_uint(f.x), ub = __float_as_uint(f.y);
    u32 uc = __float_as_uint(f.z), ud = __float_as_uint(f.w);
    ushort4 o;                                     // RNE to bf16
    o.x = (u16)((ua + 0x7fffu + ((ua >> 16) & 1u)) >> 16);
    o.y = (u16)((ub + 0x7fffu + ((ub >> 16) & 1u)) >> 16);
    o.z = (u16)((uc + 0x7fffu + ((uc >> 16) & 1u)) >> 16);
    o.w = (u16)((ud + 0x7fffu + ((ud >> 16) & 1u)) >> 16);
    ((ushort4*)dst)[i] = o;
}

// ---------------- bf16 GEMM, C = A * B^T + bias ----------------
// Round-3 kernel (BK=64, XOR-8 staging swizzle, 16x16x32 MFMA, 4x4 frags —
// the ONLY fragment-read pattern measured at SQ_LDS_BANK_CONFLICT == 0)
// + double-buffered LDS: ONE barrier per iter instead of two. The top
// barrier's compiler-emitted vmcnt(0)+lgkmcnt(0) drain guarantees both
// (a) prev staging into buf[p] visible and (b) every wave's reads of
// buf[p^1] complete -> prefetch into buf[p^1] right after it is race-free.
// LDS 64 KiB -> 2 blocks/CU, which equals the measured VGPR-capped
// occupancy anyway (no loss).
typedef const __attribute__((address_space(1))) void* gas_ptr;
typedef __attribute__((address_space(3))) void* lds_ptr;

__global__ __launch_bounds__(256, 2) void gemm_bt_bias(const u16* __restrict__ A,
                                                       const u16* __restrict__ B,
                                                       const float* __restrict__ bias,
                                                       float* __restrict__ C) {
    __shared__ u16 lA[2][BM * BK];  // 2 x 16 KiB
    __shared__ u16 lB[2][BN * BK];  // 2 x 16 KiB

    const int t = threadIdx.x;
    const int bm0 = blockIdx.y * BM;
    const int bn0 = blockIdx.x * BN;

    const int wave = t >> 6;
    const int lane = t & 63;
    const int wm = (wave & 1) * 64;
    const int wn = (wave >> 1) * 64;
    const int lr = lane & 15;          // m (A) / n (B) within 16
    const int q  = lane >> 4;          // k-quad 0..3
    const int lx = lr & 7;

    floatx4 acc[4][4] = {};

    // staging (identical to round 3): stage s, thread t -> idx = s*256+t,
    // row = idx>>3, slot = idx&7, fetch global chunk slot^(row&7).
    const u16* gA[4]; const u16* gB[4];
    int loff[4];
#pragma unroll
    for (int s = 0; s < 4; ++s) {
        const int idx = s * 256 + t;
        const int row = idx >> 3;
        const int c = (idx & 7) ^ (row & 7);       // global k-chunk (8 elems)
        gA[s] = A + (size_t)(bm0 + row) * KDIM + c * 8;
        gB[s] = B + (size_t)(bn0 + row) * KDIM + c * 8;
        loff[s] = idx * 8;                          // element offset in a buffer
    }

    // initial stage: k=0 into buf 0
#pragma unroll
    for (int s = 0; s < 4; ++s) {
        __builtin_amdgcn_global_load_lds((gas_ptr)gA[s], (lds_ptr)&lA[0][loff[s]], 16, 0, 0);
        __builtin_amdgcn_global_load_lds((gas_ptr)gB[s], (lds_ptr)&lB[0][loff[s]], 16, 0, 0);
    }

    for (int k0 = 0; k0 < KDIM; k0 += 2 * BK) {
#pragma unroll
        for (int pp = 0; pp < 2; ++pp) {
            const int kc = k0 + pp * BK;
            __syncthreads();   // buf[pp] staged+visible; all reads of buf[pp^1] drained

            // prefetch next tile into the other buffer (earliest possible issue)
            if (kc + BK < KDIM) {
                const int kn = kc + BK;
#pragma unroll
                for (int s = 0; s < 4; ++s) {
                    __builtin_amdgcn_global_load_lds((gas_ptr)(gA[s] + kn),
                                                     (lds_ptr)&lA[pp ^ 1][loff[s]], 16, 0, 0);
                    __builtin_amdgcn_global_load_lds((gas_ptr)(gB[s] + kn),
                                                     (lds_ptr)&lB[pp ^ 1][loff[s]], 16, 0, 0);
                }
            }

            // fragment reads: EXACT round-3 pattern (0-conflict verified)
            short8 af[4][2], bfr[4][2];
#pragma unroll
            for (int i = 0; i < 4; ++i) {
                const int row = wm + i * 16 + lr;
#pragma unroll
                for (int st = 0; st < 2; ++st)
                    af[i][st] = *(const short8*)&lA[pp][row * BK + (((st * 4 + q) ^ lx) * 8)];
            }
#pragma unroll
            for (int j = 0; j < 4; ++j) {
                const int row = wn + j * 16 + lr;
#pragma unroll
                for (int st = 0; st < 2; ++st)
                    bfr[j][st] = *(const short8*)&lB[pp][row * BK + (((st * 4 + q) ^ lx) * 8)];
            }

#pragma unroll
            for (int st = 0; st < 2; ++st)
#pragma unroll
                for (int i = 0; i < 4; ++i)
#pragma unroll
                    for (int j = 0; j < 4; ++j)
                        acc[i][j] = __builtin_amdgcn_mfma_f32_16x16x32_bf16(af[i][st], bfr[j][st], acc[i][j], 0, 0, 0);
        }
    }

    // epilogue: C/D layout col=lane&15, row=(lane>>4)*4+qq  [m89-verified]
#pragma unroll
    for (int i = 0; i < 4; ++i) {
        const int row0 = bm0 + wm + i * 16 + q * 4;
#pragma unroll
        for (int j = 0; j < 4; ++j) {
            const int col = bn0 + wn + j * 16 + lr;
            const float bv = bias[col];
#pragma unroll
            for (int qq = 0; qq < 4; ++qq)
                C[(size_t)(row0 + qq) * NDIM + col] = acc[i][j][qq] + bv;
        }
    }
}

extern "C" void kernel_launch(void* const* d_in, const int* in_sizes, int n_in,
                              void* d_out, int out_size, void* d_ws, size_t ws_size,
                              hipStream_t stream) {
    const float* x = (const float*)d_in[0];      // (4096, 4096) fp32
    const float* w = (const float*)d_in[1];      // (4096, 4096) fp32, OUT x IN
    const float* bias = (const float*)d_in[2];   // (4096,) fp32
    float* out = (float*)d_out;                  // (4096, 4096) fp32

    u16* xa = (u16*)d_ws;                        // 32 MiB bf16 x
    u16* wb = xa + (size_t)MDIM * KDIM;          // 32 MiB bf16 W

    const int blocks_per_mat = (MDIM * KDIM) / 4 / 256;   // 16384
    cvt2_f32_bf16<<<blocks_per_mat * 2, 256, 0, stream>>>(x, w, xa, wb);

    dim3 grid(NDIM / BN, MDIM / BM);             // 32 x 32
    gemm_bt_bias<<<grid, dim3(256), 0, stream>>>(xa, wb, bias, out);
}